// Round 5
// baseline (840.230 us; speedup 1.0000x reference)
//
#include <hip/hip_runtime.h>
#include <stdint.h>

// Problem: B=64, DIM=512, T=2048, S=1024.
// out[b][s][t] = softmax_s( 2*cross - msq[s] ),  cross = sum_d units[d][s]*H[b][d][t].
// Pipeline:
//   k_prep_units: units fp32 -> U^T bf16 hi/lo [s][d] in ws, + msq[s].
//   k_prep_h:     H fp32 [b][d][t] -> H^T bf16 hi/lo [b][t][d] in ws (LDS transpose).
//   k_fused:      FULL-S GEMM (1024 x 64 per block) via mfma_f32_32x32x16_bf16,
//                 3-term hi/lo split, fragment-order LDS (conflict-free, no swizzle),
//                 2-slot dbuf + counted vmcnt(8), setprio; in-register softmax epilogue.
// ws layout: Hh[0,128M) Hl[128M,256M) Uh Ul msq => 270,536,704 B.

typedef unsigned short u16;
typedef __attribute__((ext_vector_type(8))) short short8;    // 8 x bf16 (4 VGPR)
typedef __attribute__((ext_vector_type(4))) float f32x4;
typedef __attribute__((ext_vector_type(16))) float f32x16;   // 32x32 C/D

#define B_DIM 64
#define DIM   512
#define T_DIM 2048
#define S_DIM 1024

// fused-kernel LDS map (bytes). Slot: Ah 32K | Al 32K | Bh 2K | Bl 2K = 69632.
#define SLOT   69632
#define A_LO   32768
#define B_HI   65536
#define MSQ_O  139264        // 2*SLOT
#define REDM_O 143360
#define REDS_O 145408
#define SM_SZ  147456

__device__ __forceinline__ u16 f32_to_bf16(float f) {
  uint32_t u = __float_as_uint(f);
  uint32_t r = u + 0x7FFFu + ((u >> 16) & 1u);   // RNE
  return (u16)(r >> 16);
}
__device__ __forceinline__ float bf16_to_f32(u16 h) {
  return __uint_as_float(((uint32_t)h) << 16);
}

// ---------------- K0a: units -> U^T hi/lo + msq ----------------
__global__ __launch_bounds__(256) void k_prep_units(const float* __restrict__ units,
                                                    u16* __restrict__ Uh, u16* __restrict__ Ul,
                                                    float* __restrict__ msq) {
  const int s0 = blockIdx.x * 4;
  const int tid = threadIdx.x;
  const int lane = tid & 63, wv = tid >> 6;
  float acc0 = 0.f, acc1 = 0.f, acc2 = 0.f, acc3 = 0.f;
#pragma unroll
  for (int j = 0; j < 2; ++j) {
    const int d = tid + j * 256;
    const float4 v = *(const float4*)(units + (size_t)d * S_DIM + s0);
    acc0 += v.x * v.x; acc1 += v.y * v.y; acc2 += v.z * v.z; acc3 += v.w * v.w;
    u16 h;
    h = f32_to_bf16(v.x); Uh[(s0 + 0) * DIM + d] = h; Ul[(s0 + 0) * DIM + d] = f32_to_bf16(v.x - bf16_to_f32(h));
    h = f32_to_bf16(v.y); Uh[(s0 + 1) * DIM + d] = h; Ul[(s0 + 1) * DIM + d] = f32_to_bf16(v.y - bf16_to_f32(h));
    h = f32_to_bf16(v.z); Uh[(s0 + 2) * DIM + d] = h; Ul[(s0 + 2) * DIM + d] = f32_to_bf16(v.z - bf16_to_f32(h));
    h = f32_to_bf16(v.w); Uh[(s0 + 3) * DIM + d] = h; Ul[(s0 + 3) * DIM + d] = f32_to_bf16(v.w - bf16_to_f32(h));
  }
#pragma unroll
  for (int off = 1; off < 64; off <<= 1) {
    acc0 += __shfl_xor(acc0, off);
    acc1 += __shfl_xor(acc1, off);
    acc2 += __shfl_xor(acc2, off);
    acc3 += __shfl_xor(acc3, off);
  }
  __shared__ float part[4][4];
  if (lane == 0) { part[wv][0] = acc0; part[wv][1] = acc1; part[wv][2] = acc2; part[wv][3] = acc3; }
  __syncthreads();
  if (tid < 4) msq[s0 + tid] = part[0][tid] + part[1][tid] + part[2][tid] + part[3][tid];
}

// ---------------- K0b: H [b][d][t] -> H^T hi/lo [b][t][d] ----------------
__global__ __launch_bounds__(256) void k_prep_h(const float* __restrict__ H,
                                                u16* __restrict__ Hh, u16* __restrict__ Hl) {
  __shared__ float tile[64 * 68];
  const int t0 = blockIdx.x * 64, d0 = blockIdx.y * 64, b = blockIdx.z;
  const int tid = threadIdx.x;
#pragma unroll
  for (int j = 0; j < 4; ++j) {
    const int chunk = tid + j * 256;
    const int r = chunk >> 4, c4 = (chunk & 15) * 4;
    const float4 v = *(const float4*)(H + ((size_t)(b * DIM + d0 + r)) * T_DIM + t0 + c4);
    *(float4*)(&tile[r * 68 + c4]) = v;
  }
  __syncthreads();
#pragma unroll
  for (int j = 0; j < 2; ++j) {
    const int chunk = tid + j * 256;
    const int q = chunk >> 3, e8 = (chunk & 7) * 8;
    union { u16 us[8]; uint4 v4; } hi, lo;
#pragma unroll
    for (int k = 0; k < 8; ++k) {
      const float f = tile[(e8 + k) * 68 + q];
      const u16 h = f32_to_bf16(f);
      hi.us[k] = h;
      lo.us[k] = f32_to_bf16(f - bf16_to_f32(h));
    }
    const size_t o = ((size_t)(b * T_DIM + t0 + q)) * DIM + d0 + e8;
    *(uint4*)(Hh + o) = hi.v4;
    *(uint4*)(Hl + o) = lo.v4;
  }
}

// ---------------- K1: fused GEMM (32x32x16) + softmax ----------------
__device__ __forceinline__ void gl16(const void* g, void* l) {
  __builtin_amdgcn_global_load_lds((const __attribute__((address_space(1))) void*)g,
                                   (__attribute__((address_space(3))) void*)l, 16, 0, 0);
}

#define WAITV(N) asm volatile("s_waitcnt vmcnt(" #N ")" ::: "memory")
#define SYNCPT() do { __builtin_amdgcn_s_barrier(); __builtin_amdgcn_sched_barrier(0); } while (0)

__global__ __launch_bounds__(512, 2) void k_fused(const u16* __restrict__ Uh, const u16* __restrict__ Ul,
                                                  const u16* __restrict__ Hh, const u16* __restrict__ Hl,
                                                  const float* __restrict__ msq,
                                                  float* __restrict__ out) {
  __shared__ __align__(16) char sm[SM_SZ];
  const int tid = threadIdx.x;
  const int lane = tid & 63, wv = tid >> 6;
  const int l31 = lane & 31, lhi = lane >> 5;
  const int lane16 = lane * 16;

  const int t00 = blockIdx.x * 64;
  const int bb = blockIdx.y;

  // ---- staging geometry (fragment-order LDS: dest = region + chunk*16) ----
  // A-chunk c (0..2047 per hi/lo): tile ts=c>>6 covers s rows ts*32..+31;
  //   element: s = ts*32 + (c&31), khalf = (c>>5)&1. Thread does c_i = tid + i*512.
  // Source: U^T row-major [s][512d], 2B/elem: addr = s*1024 + kslab*32 + khalf*16.
  int aSrc[4], aDst[4];
#pragma unroll
  for (int i = 0; i < 4; ++i) {
    const int ci = tid + i * 512;
    const int si = (ci >> 6) * 32 + (ci & 31);
    aSrc[i] = si * 1024 + (((ci >> 5) & 1) << 4);
    aDst[i] = ci * 16;
  }
  // B-chunk c (0..127): t = (c>>6)*32 + (c&31), khalf = (c>>5)&1.
  const int cB = tid & 127;
  const int tB = (cB >> 6) * 32 + (cB & 31);
  const size_t bSrc = ((size_t)(bb * T_DIM + t00 + tB)) * 1024 + (size_t)(((cB >> 5) & 1) << 4);
  const int bDst = B_HI + tid * 16;              // tid<128 -> Bh, 128..255 -> Bl (contiguous)
  const char* const pAh = (const char*)Uh;
  const char* const pAl = (const char*)Ul;
  const char* const pBsel = (tid < 128) ? (const char*)Hh : (const char*)Hl;

#define STAGE(SLOTB, KS) do {                                             \
    const int ko = (KS) * 32;                                             \
    char* d = sm + (SLOTB);                                               \
    gl16(pAh + aSrc[0] + ko, d + aDst[0]);                                \
    gl16(pAh + aSrc[1] + ko, d + aDst[1]);                                \
    gl16(pAh + aSrc[2] + ko, d + aDst[2]);                                \
    gl16(pAh + aSrc[3] + ko, d + aDst[3]);                                \
    gl16(pAl + aSrc[0] + ko, d + A_LO + aDst[0]);                         \
    gl16(pAl + aSrc[1] + ko, d + A_LO + aDst[1]);                         \
    gl16(pAl + aSrc[2] + ko, d + A_LO + aDst[2]);                         \
    gl16(pAl + aSrc[3] + ko, d + A_LO + aDst[3]);                         \
    if (tid < 256) gl16(pBsel + bSrc + ko, d + bDst);                     \
  } while (0)

  // wave sw owns s rows [sw*128, +128) = 4 tiles of 32; all 64 t = 2 tiles.
  const int sw = wv;

  f32x16 acc[4][2];
#pragma unroll
  for (int mt = 0; mt < 4; ++mt)
#pragma unroll
    for (int nt = 0; nt < 2; ++nt)
#pragma unroll
      for (int r = 0; r < 16; ++r)
        acc[mt][nt][r] = 0.f;

#define COMPUTE(SLOTB) do {                                               \
    const char* sl = sm + (SLOTB);                                        \
    short8 ah[4], al[4], bh[2], bl[2];                                    \
    _Pragma("unroll") for (int mt = 0; mt < 4; ++mt) {                    \
      ah[mt] = *(const short8*)(sl + (sw * 4 + mt) * 1024 + lane16);      \
      al[mt] = *(const short8*)(sl + A_LO + (sw * 4 + mt) * 1024 + lane16); \
    }                                                                     \
    _Pragma("unroll") for (int nt = 0; nt < 2; ++nt) {                    \
      bh[nt] = *(const short8*)(sl + B_HI + nt * 1024 + lane16);          \
      bl[nt] = *(const short8*)(sl + B_HI + 2048 + nt * 1024 + lane16);   \
    }                                                                     \
    __builtin_amdgcn_s_setprio(1);                                        \
    _Pragma("unroll") for (int mt = 0; mt < 4; ++mt)                      \
      _Pragma("unroll") for (int nt = 0; nt < 2; ++nt) {                  \
        acc[mt][nt] = __builtin_amdgcn_mfma_f32_32x32x16_bf16(ah[mt], bh[nt], acc[mt][nt], 0, 0, 0); \
        acc[mt][nt] = __builtin_amdgcn_mfma_f32_32x32x16_bf16(ah[mt], bl[nt], acc[mt][nt], 0, 0, 0); \
        acc[mt][nt] = __builtin_amdgcn_mfma_f32_32x32x16_bf16(al[mt], bh[nt], acc[mt][nt], 0, 0, 0); \
      }                                                                   \
    __builtin_amdgcn_s_setprio(0);                                        \
  } while (0)

  // ---- prologue ----
  if (tid < 256) gl16((const char*)msq + tid * 16, sm + MSQ_O + tid * 16);
  STAGE(0, 0);
  STAGE(SLOT, 1);

#pragma unroll 1
  for (int k = 0; k < 31; ++k) {
    WAITV(8);                     // per-wave: drains slab k (waves 0-3 have 9/slab, 4-7 have 8)
    SYNCPT();                     // cross-wave: slab k fully in LDS
    COMPUTE((k & 1) * SLOT);
    SYNCPT();                     // all waves done reading this slot
    if (k < 30) STAGE((k & 1) * SLOT, k + 2);
  }
  WAITV(0);
  SYNCPT();
  COMPUTE(SLOT);                  // slab 31 (odd slot)

  // ---- epilogue: softmax over s, in registers ----
  // C/D 32x32: col(t) = lane&31, row-in-tile = (reg&3) + 8*(reg>>2) + 4*lhi.
  const float* msql = (const float*)(sm + MSQ_O);
  float* redM = (float*)(sm + REDM_O);   // [8][64]
  float* redS = (float*)(sm + REDS_O);

  float mx0 = -3.0e38f, mx1 = -3.0e38f;
#pragma unroll
  for (int mt = 0; mt < 4; ++mt) {
    const int sb = sw * 128 + mt * 32 + lhi * 4;
#pragma unroll
    for (int q = 0; q < 4; ++q) {
      const f32x4 mq = *(const f32x4*)(msql + sb + q * 8);
#pragma unroll
      for (int r = 0; r < 4; ++r) {
        const int reg = q * 4 + r;
        const float v0 = 2.f * acc[mt][0][reg] - mq[r];
        const float v1 = 2.f * acc[mt][1][reg] - mq[r];
        acc[mt][0][reg] = v0; acc[mt][1][reg] = v1;
        mx0 = fmaxf(mx0, v0); mx1 = fmaxf(mx1, v1);
      }
    }
  }
  mx0 = fmaxf(mx0, __shfl_xor(mx0, 32));
  mx1 = fmaxf(mx1, __shfl_xor(mx1, 32));
  if (lane < 32) { redM[wv * 64 + l31] = mx0; redM[wv * 64 + 32 + l31] = mx1; }
  __syncthreads();
  float M0 = redM[l31], M1 = redM[32 + l31];
#pragma unroll
  for (int w = 1; w < 8; ++w) {
    M0 = fmaxf(M0, redM[w * 64 + l31]);
    M1 = fmaxf(M1, redM[w * 64 + 32 + l31]);
  }
  float s0 = 0.f, s1 = 0.f;
#pragma unroll
  for (int mt = 0; mt < 4; ++mt)
#pragma unroll
    for (int reg = 0; reg < 16; ++reg) {
      const float e0 = __expf(acc[mt][0][reg] - M0);
      const float e1 = __expf(acc[mt][1][reg] - M1);
      acc[mt][0][reg] = e0; acc[mt][1][reg] = e1;
      s0 += e0; s1 += e1;
    }
  s0 += __shfl_xor(s0, 32);
  s1 += __shfl_xor(s1, 32);
  if (lane < 32) { redS[wv * 64 + l31] = s0; redS[wv * 64 + 32 + l31] = s1; }
  __syncthreads();
  float S0 = redS[l31], S1 = redS[32 + l31];
#pragma unroll
  for (int w = 1; w < 8; ++w) {
    S0 += redS[w * 64 + l31];
    S1 += redS[w * 64 + 32 + l31];
  }
  const float r0 = 1.0f / S0, r1 = 1.0f / S1;

  float* const outb = out + ((size_t)bb << 21);   // b * 1024 * 2048
  const int tc0 = t00 + l31, tc1 = t00 + 32 + l31;
#pragma unroll
  for (int mt = 0; mt < 4; ++mt) {
    const int sb = sw * 128 + mt * 32 + lhi * 4;
#pragma unroll
    for (int q = 0; q < 4; ++q)
#pragma unroll
      for (int r = 0; r < 4; ++r) {
        const int srow = sb + q * 8 + r;
        const int reg = q * 4 + r;
        outb[(size_t)srow * T_DIM + tc0] = acc[mt][0][reg] * r0;
        outb[(size_t)srow * T_DIM + tc1] = acc[mt][1][reg] * r1;
      }
  }
}

// ---------------- launch ----------------
extern "C" void kernel_launch(void* const* d_in, const int* in_sizes, int n_in,
                              void* d_out, int out_size, void* d_ws, size_t ws_size,
                              hipStream_t stream) {
  (void)in_sizes; (void)n_in; (void)out_size; (void)ws_size;
  const float* H = (const float*)d_in[0];
  const float* units = (const float*)d_in[1];
  float* out = (float*)d_out;
  char* ws = (char*)d_ws;
  u16* Hh = (u16*)(ws);
  u16* Hl = (u16*)(ws + 134217728);
  u16* Uh = (u16*)(ws + 268435456);
  u16* Ul = (u16*)(ws + 269484032);
  float* msq = (float*)(ws + 270532608);

  k_prep_units<<<dim3(S_DIM / 4), 256, 0, stream>>>(units, Uh, Ul, msq);
  k_prep_h<<<dim3(T_DIM / 64, DIM / 64, B_DIM), 256, 0, stream>>>(H, Hh, Hl);
  k_fused<<<dim3(T_DIM / 64, B_DIM), 512, 0, stream>>>(Uh, Ul, Hh, Hl, msq, out);
}

// Round 6
// 592.585 us; speedup vs baseline: 1.4179x; 1.4179x over previous
//
#include <hip/hip_runtime.h>
#include <stdint.h>

// Problem: B=64, DIM=512, T=2048, S=1024.
// out[b][s][t] = softmax_s( 2*cross - msq[s] ),  cross = sum_d units[d][s]*H[b][d][t].
// Pipeline:
//   k_prep_units: units fp32 -> Upack hi/lo (MFMA-fragment-slab order) + msq[s].
//   k_prep_h:     H fp32 -> Bpack hi/lo (fragment-slab order per (b, t-group-64)).
//   k_fused:      FULL-S GEMM (1024x64/block) 32x32x16 MFMA, 3-term hi/lo,
//                 wave-local A staging (no cross-wave A barrier), 4-deep B ring,
//                 counted vmcnt 4/5 (never 0), 1 barrier/slab, 3 phases/slab,
//                 setprio; in-register softmax epilogue.
// ws: BpackH[0,128M) BpackL[128M,256M) UpackH(1M) UpackL(1M) msq(4K) => ~258 MB.

typedef unsigned short u16;
typedef __attribute__((ext_vector_type(8))) short short8;    // 8 x bf16 (4 VGPR)
typedef __attribute__((ext_vector_type(4))) float f32x4;
typedef __attribute__((ext_vector_type(16))) float f32x16;   // 32x32 C/D

#define B_DIM 64
#define DIM   512
#define T_DIM 2048
#define S_DIM 1024

// k_fused LDS map (bytes)
#define ASLOT0 0
#define ASLOT1 65536          // A slot = Ah 32K @ +0 | Al 32K @ +32768
#define A_LO   32768
#define BRING  131072         // 4 x 4096 (Bh 2K | Bl 2K per slot)
#define MSQ_O  147456         // 4 KB
#define REDM_O 151552         // 2 KB
#define REDS_O 153600         // 2 KB
#define SM_SZ  155648

__device__ __forceinline__ u16 f32_to_bf16(float f) {
  uint32_t u = __float_as_uint(f);
  uint32_t r = u + 0x7FFFu + ((u >> 16) & 1u);   // RNE
  return (u16)(r >> 16);
}
__device__ __forceinline__ float bf16_to_f32(u16 h) {
  return __uint_as_float(((uint32_t)h) << 16);
}

// Fragment-chunk math (verified via R5 pass):
//   A chunk ci (per slab ks): ts=ci>>6 (32-s tile), s=ts*32+(ci&31), khalf=(ci>>5)&1,
//     elem e=0..7 -> d = ks*16 + khalf*8 + e.  LDS byte = ci*16 + e*2.
//   B chunk cB: nt=cB>>6, t=nt*32+(cB&31), khalf=(cB>>5)&1, d likewise.

// ---------------- K0a: units -> Upack hi/lo + msq ----------------
__global__ __launch_bounds__(256) void k_prep_units(const float* __restrict__ units,
                                                    u16* __restrict__ UpH, u16* __restrict__ UpL,
                                                    float* __restrict__ msq) {
  const int s0 = blockIdx.x * 4;
  const int tid = threadIdx.x;
  const int lane = tid & 63, wv = tid >> 6;
  float acc0 = 0.f, acc1 = 0.f, acc2 = 0.f, acc3 = 0.f;
#pragma unroll
  for (int j = 0; j < 2; ++j) {
    const int d = tid + j * 256;
    const float4 v = *(const float4*)(units + (size_t)d * S_DIM + s0);
    acc0 += v.x * v.x; acc1 += v.y * v.y; acc2 += v.z * v.z; acc3 += v.w * v.w;
    // dest u16 idx for (s,d): (d>>4)*16384 + ((s>>5)*64 + ((d>>3)&1)*32 + (s&31))*8 + (d&7)
    const int dbase = (d >> 4) * 16384 + ((d >> 3) & 1) * 256 + (d & 7);
    const float fv[4] = {v.x, v.y, v.z, v.w};
#pragma unroll
    for (int q = 0; q < 4; ++q) {
      const int s = s0 + q;
      const int idx = dbase + ((s >> 5) * 64 + (s & 31)) * 8;
      const u16 h = f32_to_bf16(fv[q]);
      UpH[idx] = h;
      UpL[idx] = f32_to_bf16(fv[q] - bf16_to_f32(h));
    }
  }
#pragma unroll
  for (int off = 1; off < 64; off <<= 1) {
    acc0 += __shfl_xor(acc0, off);
    acc1 += __shfl_xor(acc1, off);
    acc2 += __shfl_xor(acc2, off);
    acc3 += __shfl_xor(acc3, off);
  }
  __shared__ float part[4][4];
  if (lane == 0) { part[wv][0] = acc0; part[wv][1] = acc1; part[wv][2] = acc2; part[wv][3] = acc3; }
  __syncthreads();
  if (tid < 4) msq[s0 + tid] = part[0][tid] + part[1][tid] + part[2][tid] + part[3][tid];
}

// ---------------- K0b: H [b][d][t] -> Bpack hi/lo ----------------
__global__ __launch_bounds__(256) void k_prep_h(const float* __restrict__ H,
                                                u16* __restrict__ BpH, u16* __restrict__ BpL) {
  __shared__ float tile[64 * 68];
  const int bx = blockIdx.x;                 // t-group (64 t)
  const int d0 = blockIdx.y * 64;
  const int b = blockIdx.z;
  const int t0 = bx * 64;
  const int tid = threadIdx.x;
#pragma unroll
  for (int j = 0; j < 4; ++j) {
    const int chunk = tid + j * 256;
    const int r = chunk >> 4, c4 = (chunk & 15) * 4;
    const float4 v = *(const float4*)(H + ((size_t)(b * DIM + d0 + r)) * T_DIM + t0 + c4);
    *(float4*)(&tile[r * 68 + c4]) = v;
  }
  __syncthreads();
#pragma unroll
  for (int j = 0; j < 2; ++j) {
    const int chunk = tid + j * 256;
    const int q = chunk >> 3, e8 = (chunk & 7) * 8;   // t-local q, d-local group e8
    union { u16 us[8]; uint4 v4; } hi, lo;
#pragma unroll
    for (int k = 0; k < 8; ++k) {
      const float f = tile[(e8 + k) * 68 + q];
      const u16 h = f32_to_bf16(f);
      hi.us[k] = h;
      lo.us[k] = f32_to_bf16(f - bf16_to_f32(h));
    }
    const int dg = d0 + e8;
    const int chunkB = (q >> 5) * 64 + ((dg >> 3) & 1) * 32 + (q & 31);
    const size_t o = ((((size_t)b * 32 + bx) * 32 + (dg >> 4)) * 128 + chunkB) * 8;
    *(uint4*)(BpH + o) = hi.v4;
    *(uint4*)(BpL + o) = lo.v4;
  }
}

// ---------------- K1: fused GEMM (32x32x16) + softmax ----------------
__device__ __forceinline__ void gl16(const void* g, void* l) {
  __builtin_amdgcn_global_load_lds((const __attribute__((address_space(1))) void*)g,
                                   (__attribute__((address_space(3))) void*)l, 16, 0, 0);
}

#define WAITV(N) asm volatile("s_waitcnt vmcnt(" #N ")" ::: "memory")
#define SYNCPT() do { __builtin_amdgcn_s_barrier(); __builtin_amdgcn_sched_barrier(0); } while (0)

__global__ __launch_bounds__(512, 2) void k_fused(const u16* __restrict__ UpH, const u16* __restrict__ UpL,
                                                  const u16* __restrict__ BpH, const u16* __restrict__ BpL,
                                                  const float* __restrict__ msq,
                                                  float* __restrict__ out) {
  __shared__ __align__(16) char sm[SM_SZ];
  const int tid = threadIdx.x;
  const int lane = tid & 63, wv = tid >> 6;
  const int l31 = lane & 31, lhi = lane >> 5;
  const int sw = wv;                // wave owns s rows [sw*128, +128) = tiles sw*4..+3
  const int g = wv & 3;             // B/msq staging group (duplicated by wv>=4)

  const int tgx = blockIdx.x;       // t-group (64 t)
  const int t00 = tgx * 64;
  const int bb = blockIdx.y;

  // ---- staging sources (contiguous 1KB per wave-inst) ----
  const char* const upH = (const char*)UpH + (size_t)(sw * 256 + lane) * 16;  // + i*1024 + ks*32768
  const char* const upL = (const char*)UpL + (size_t)(sw * 256 + lane) * 16;
  const char* const bp = ((g < 2) ? (const char*)BpH : (const char*)BpL)
                         + (((size_t)bb * 32 + tgx) * 32) * 2048
                         + (size_t)((g & 1) * 64 + lane) * 16;                // + ks*2048
  // ---- staging dests (linear, wave-local A) ----
  const int dA = (sw * 256 + lane) * 16;        // + i*1024 (+A_LO for lo) + slot
  const int dB = BRING + ((g < 2) ? 0 : 2048) + ((g & 1) * 64 + lane) * 16;   // + ring*4096

#define ST_AH(SL, KS, I) gl16(upH + (size_t)(KS) * 32768 + (I) * 1024, sm + (SL) + (I) * 1024 + dA)
#define ST_AL(SL, KS, I) gl16(upL + (size_t)(KS) * 32768 + (I) * 1024, sm + (SL) + A_LO + (I) * 1024 + dA)
#define ST_B(KS)         gl16(bp + (size_t)(KS) * 2048, sm + (((KS) & 3) * 4096) + dB)

  // ---- fragment read offsets ----
  const int offA = sw * 4096 + lane * 16;       // + mt*1024 + slot (+A_LO)
  const int offB = lane * 16;                   // + ring*4096 + nt*1024 (+2048 for lo)

  f32x16 acc[4][2];
#pragma unroll
  for (int mt = 0; mt < 4; ++mt)
#pragma unroll
    for (int nt = 0; nt < 2; ++nt)
#pragma unroll
      for (int r = 0; r < 16; ++r)
        acc[mt][nt][r] = 0.f;

  // ---- prologue: 11 loads/wave: msq, B(0), Ah(0)x4, Al(0)x4, B(1) ----
  gl16((const char*)msq + g * 1024 + lane * 16, sm + MSQ_O + g * 1024 + lane * 16);
  ST_B(0);
  ST_AH(ASLOT0, 0, 0); ST_AH(ASLOT0, 0, 1); ST_AH(ASLOT0, 0, 2); ST_AH(ASLOT0, 0, 3);
  ST_AL(ASLOT0, 0, 0); ST_AL(ASLOT0, 0, 1); ST_AL(ASLOT0, 0, 2); ST_AL(ASLOT0, 0, 3);
  ST_B(1);

#pragma unroll 1
  for (int k = 0; k < 32; ++k) {
    const int cur = (k & 1) << 16;
    const int nxt = 65536 - cur;
    const int ksA = (k + 1 < 32) ? (k + 1) : 31;    // clamped tail restage (keeps counts uniform)
    const int ksB = (k + 2 < 32) ? (k + 2) : 31;
    const int rb = BRING + (k & 3) * 4096;

    WAITV(4);        // drains B(k+1-early), Ah(k); leaves Al(k) x4
    SYNCPT();        // slab k fully visible to all waves

    short8 ah[4], al[4], bh[2], bl[2];
    // ---- P1: AhBh ----
#pragma unroll
    for (int mt = 0; mt < 4; ++mt) ah[mt] = *(const short8*)(sm + cur + offA + mt * 1024);
    bh[0] = *(const short8*)(sm + rb + offB);
    bh[1] = *(const short8*)(sm + rb + 1024 + offB);
    ST_B(ksB);
    ST_AH(nxt, ksA, 0); ST_AH(nxt, ksA, 1);
    __builtin_amdgcn_s_setprio(1);
#pragma unroll
    for (int mt = 0; mt < 4; ++mt) {
      acc[mt][0] = __builtin_amdgcn_mfma_f32_32x32x16_bf16(ah[mt], bh[0], acc[mt][0], 0, 0, 0);
      acc[mt][1] = __builtin_amdgcn_mfma_f32_32x32x16_bf16(ah[mt], bh[1], acc[mt][1], 0, 0, 0);
    }
    __builtin_amdgcn_s_setprio(0);
    // ---- P2: AhBl ----
    bl[0] = *(const short8*)(sm + rb + 2048 + offB);
    bl[1] = *(const short8*)(sm + rb + 3072 + offB);
    ST_AH(nxt, ksA, 2); ST_AH(nxt, ksA, 3);
    __builtin_amdgcn_s_setprio(1);
#pragma unroll
    for (int mt = 0; mt < 4; ++mt) {
      acc[mt][0] = __builtin_amdgcn_mfma_f32_32x32x16_bf16(ah[mt], bl[0], acc[mt][0], 0, 0, 0);
      acc[mt][1] = __builtin_amdgcn_mfma_f32_32x32x16_bf16(ah[mt], bl[1], acc[mt][1], 0, 0, 0);
    }
    __builtin_amdgcn_s_setprio(0);
    // ---- P3: AlBh ----
    WAITV(5);        // drains Al(k); leaves B(k+2), Ah(k+1) x4
#pragma unroll
    for (int mt = 0; mt < 4; ++mt) al[mt] = *(const short8*)(sm + cur + A_LO + offA + mt * 1024);
    ST_AL(nxt, ksA, 0); ST_AL(nxt, ksA, 1); ST_AL(nxt, ksA, 2); ST_AL(nxt, ksA, 3);
    __builtin_amdgcn_s_setprio(1);
#pragma unroll
    for (int mt = 0; mt < 4; ++mt) {
      acc[mt][0] = __builtin_amdgcn_mfma_f32_32x32x16_bf16(al[mt], bh[0], acc[mt][0], 0, 0, 0);
      acc[mt][1] = __builtin_amdgcn_mfma_f32_32x32x16_bf16(al[mt], bh[1], acc[mt][1], 0, 0, 0);
    }
    __builtin_amdgcn_s_setprio(0);
  }

  // ---- epilogue: softmax over s, in registers (R5-verified mapping) ----
  // s = sw*128 + mt*32 + lhi*4 + q*8 + r (reg = q*4+r); t = t00 + nt*32 + l31.
  const float* msql = (const float*)(sm + MSQ_O);
  float* redM = (float*)(sm + REDM_O);   // [8][64]
  float* redS = (float*)(sm + REDS_O);

  float mx0 = -3.0e38f, mx1 = -3.0e38f;
#pragma unroll
  for (int mt = 0; mt < 4; ++mt) {
    const int sb = sw * 128 + mt * 32 + lhi * 4;
#pragma unroll
    for (int q = 0; q < 4; ++q) {
      const f32x4 mq = *(const f32x4*)(msql + sb + q * 8);
#pragma unroll
      for (int r = 0; r < 4; ++r) {
        const int reg = q * 4 + r;
        const float v0 = 2.f * acc[mt][0][reg] - mq[r];
        const float v1 = 2.f * acc[mt][1][reg] - mq[r];
        acc[mt][0][reg] = v0; acc[mt][1][reg] = v1;
        mx0 = fmaxf(mx0, v0); mx1 = fmaxf(mx1, v1);
      }
    }
  }
  mx0 = fmaxf(mx0, __shfl_xor(mx0, 32));
  mx1 = fmaxf(mx1, __shfl_xor(mx1, 32));
  if (lane < 32) { redM[wv * 64 + l31] = mx0; redM[wv * 64 + 32 + l31] = mx1; }
  __syncthreads();
  float M0 = redM[l31], M1 = redM[32 + l31];
#pragma unroll
  for (int w = 1; w < 8; ++w) {
    M0 = fmaxf(M0, redM[w * 64 + l31]);
    M1 = fmaxf(M1, redM[w * 64 + 32 + l31]);
  }
  float s0 = 0.f, s1 = 0.f;
#pragma unroll
  for (int mt = 0; mt < 4; ++mt)
#pragma unroll
    for (int reg = 0; reg < 16; ++reg) {
      const float e0 = __expf(acc[mt][0][reg] - M0);
      const float e1 = __expf(acc[mt][1][reg] - M1);
      acc[mt][0][reg] = e0; acc[mt][1][reg] = e1;
      s0 += e0; s1 += e1;
    }
  s0 += __shfl_xor(s0, 32);
  s1 += __shfl_xor(s1, 32);
  if (lane < 32) { redS[wv * 64 + l31] = s0; redS[wv * 64 + 32 + l31] = s1; }
  __syncthreads();
  float S0 = redS[l31], S1 = redS[32 + l31];
#pragma unroll
  for (int w = 1; w < 8; ++w) {
    S0 += redS[w * 64 + l31];
    S1 += redS[w * 64 + 32 + l31];
  }
  const float r0 = 1.0f / S0, r1 = 1.0f / S1;

  float* const outb = out + ((size_t)bb << 21);   // b * 1024 * 2048
  const int tc0 = t00 + l31, tc1 = t00 + 32 + l31;
#pragma unroll
  for (int mt = 0; mt < 4; ++mt) {
    const int sb = sw * 128 + mt * 32 + lhi * 4;
#pragma unroll
    for (int q = 0; q < 4; ++q)
#pragma unroll
      for (int r = 0; r < 4; ++r) {
        const int srow = sb + q * 8 + r;
        const int reg = q * 4 + r;
        outb[(size_t)srow * T_DIM + tc0] = acc[mt][0][reg] * r0;
        outb[(size_t)srow * T_DIM + tc1] = acc[mt][1][reg] * r1;
      }
  }
}

// ---------------- launch ----------------
extern "C" void kernel_launch(void* const* d_in, const int* in_sizes, int n_in,
                              void* d_out, int out_size, void* d_ws, size_t ws_size,
                              hipStream_t stream) {
  (void)in_sizes; (void)n_in; (void)out_size; (void)ws_size;
  const float* H = (const float*)d_in[0];
  const float* units = (const float*)d_in[1];
  float* out = (float*)d_out;
  char* ws = (char*)d_ws;
  u16* BpH = (u16*)(ws);
  u16* BpL = (u16*)(ws + 134217728);
  u16* UpH = (u16*)(ws + 268435456);
  u16* UpL = (u16*)(ws + 269484032);
  float* msq = (float*)(ws + 270532608);

  k_prep_units<<<dim3(S_DIM / 4), 256, 0, stream>>>(units, UpH, UpL, msq);
  k_prep_h<<<dim3(T_DIM / 64, DIM / 64, B_DIM), 256, 0, stream>>>(H, BpH, BpL);
  k_fused<<<dim3(T_DIM / 64, B_DIM), 512, 0, stream>>>(UpH, UpL, BpH, BpL, msq, out);
}